// Round 2
// baseline (49.031 us; speedup 1.0000x reference)
//
#include <hip/hip_runtime.h>

#define B_ 16
#define U_ 500
#define S_ 256
#define H_ 128
#define UTILE 32
#define NWAVES 16
#define TPB (NWAVES * 64)

__global__ __launch_bounds__(TPB, 1) void attn_kernel(
    const float* __restrict__ user,     // (B,U,4)
    const float* __restrict__ server,   // (B,S,6)
    const int*   __restrict__ masks,    // (B,U,S) int32 0/1 OR packed bytes (auto-detected)
    const float* __restrict__ Wu,       // (3,H)
    const float* __restrict__ bu,       // (H)
    const float* __restrict__ Ws,       // (7,H)  (row 6 multiplies the zero 'active' col -> unused)
    const float* __restrict__ bs,       // (H)
    const float* __restrict__ W1,       // (H,H)
    const float* __restrict__ W2,       // (H,H)
    const float* __restrict__ vt,       // (H)
    float* __restrict__ out)            // (B,U,S) fp32
{
  __shared__ float E[H_][S_];          // 128 KB, transposed [h][s], holds exp(2*enc)
  __shared__ float M1s[6 * H_];        // Ws@W1 (rows 0..5)
  __shared__ float M2s[3 * H_];        // Wu@W2
  __shared__ float c1s[H_];            // bs@W1
  __shared__ float c2s[H_];            // bu@W2
  __shared__ float decs[8][4][H_];     // exp(2*dec): 8 row-groups x 4 u-rows
  __shared__ float redmax[8][4][2];    // cross-s-half softmax partials
  __shared__ float redsum[8][4][2];
  __shared__ float vsum_s;

  const int tid = threadIdx.x;
  const int bid = blockIdx.x;
  const int b   = bid >> 4;
  const int u0  = (bid & 15) * UTILE;

  // ---- phase 0: fused weight products (redundant per block, negligible) ----
  {
    const int h = tid & (H_ - 1);
    for (int job = tid >> 7; job < 11; job += 8) {
      const float* Lv; const float* Rm; float* dst;
      if (job < 6)       { Lv = Ws + job * H_;       Rm = W1; dst = M1s + job * H_; }
      else if (job == 6) { Lv = bs;                  Rm = W1; dst = c1s; }
      else if (job < 10) { Lv = Wu + (job - 7) * H_; Rm = W2; dst = M2s + (job - 7) * H_; }
      else               { Lv = bu;                  Rm = W2; dst = c2s; }
      float acc = 0.f;
      for (int j = 0; j < H_; ++j) acc = fmaf(Lv[j], Rm[j * H_ + h], acc);
      dst[h] = acc;
    }
    if (tid < 64) {                       // vsum = sum(vt), from global (no LDS dep)
      float v = vt[tid] + vt[tid + 64];
      #pragma unroll
      for (int off = 32; off > 0; off >>= 1) v += __shfl_xor(v, off, 64);
      if (tid == 0) vsum_s = v;
    }
  }

  // ---- mask dtype detection: int32 masks are strictly 0/1; packed bools make words >1 ----
  int lflag;
  {
    int4 mw = *reinterpret_cast<const int4*>(masks + tid * 4);   // first 4096 words, in-bounds either way
    lflag = ((unsigned)mw.x > 1u) | ((unsigned)mw.y > 1u) |
            ((unsigned)mw.z > 1u) | ((unsigned)mw.w > 1u);
  }
  const int bytemode = __syncthreads_or(lflag);   // barrier also publishes phase-0 LDS

  // ---- phase 1: stage E[h][s] = exp(2*(c1[h] + sum_k server[b,s,k]*M1[k][h])) ----
  {
    const int s  = tid & (S_ - 1);
    const int h0 = tid >> 8;   // 0..3, wave-uniform
    const float2* sv = reinterpret_cast<const float2*>(server + ((size_t)b * S_ + s) * 6);
    const float2 p0 = sv[0], p1 = sv[1], p2 = sv[2];
    for (int h = h0; h < H_; h += 4) {
      float a = c1s[h];
      a = fmaf(p0.x, M1s[0 * H_ + h], a);
      a = fmaf(p0.y, M1s[1 * H_ + h], a);
      a = fmaf(p1.x, M1s[2 * H_ + h], a);
      a = fmaf(p1.y, M1s[3 * H_ + h], a);
      a = fmaf(p2.x, M1s[4 * H_ + h], a);
      a = fmaf(p2.y, M1s[5 * H_ + h], a);
      E[h][s] = __expf(fminf(fmaxf(a + a, -60.f), 60.f));
    }
  }

  // wave decomposition: wave = (row-group rg, s-half sh); lane owns s0,s0+1 for 4 u-rows
  const int w    = tid >> 6;
  const int lane = tid & 63;
  const int rg   = w >> 1;              // 0..7 -> u-rows u0+4*rg .. u0+4*rg+3
  const int sh   = w & 1;               // 0/1  -> s in [sh*128, sh*128+128)
  const int s0   = sh * 128 + 2 * lane;

  // ---- dec rows: this wave computes rows (2*sh, 2*sh+1) of its group; pair covers all 4 ----
  {
    #pragma unroll
    for (int rr = 0; rr < 2; ++rr) {
      const int r  = 2 * sh + rr;
      const int uc = min(u0 + rg * 4 + r, U_ - 1);
      const float* uv = user + ((size_t)b * U_ + uc) * 4;
      const float g0 = uv[0], g1 = uv[1], g2 = uv[2];
      #pragma unroll
      for (int hh = 0; hh < 2; ++hh) {
        const int h = lane + hh * 64;
        float a = c2s[h];
        a = fmaf(g0, M2s[0 * H_ + h], a);
        a = fmaf(g1, M2s[1 * H_ + h], a);
        a = fmaf(g2, M2s[2 * H_ + h], a);
        decs[rg][r][h] = __expf(fminf(fmaxf(a + a, -60.f), 60.f));
      }
    }
  }
  __syncthreads();   // publishes E + decs (cross-wave-pair)

  // ---- issue mask loads early to hide HBM latency under the main loop ----
  size_t ridx[4]; int uval[4]; int m0[4], m1[4];
  #pragma unroll
  for (int r = 0; r < 4; ++r) {
    const int u = u0 + rg * 4 + r;
    uval[r] = (u < U_);
    ridx[r] = ((size_t)b * U_ + min(u, U_ - 1)) * S_ + s0;
  }
  if (!bytemode) {
    #pragma unroll
    for (int r = 0; r < 4; ++r) {
      int2 mm = *reinterpret_cast<const int2*>(masks + ridx[r]);
      m0[r] = mm.x; m1[r] = mm.y;
    }
  } else {
    const unsigned char* mb = reinterpret_cast<const unsigned char*>(masks);
    #pragma unroll
    for (int r = 0; r < 4; ++r) {
      uchar2 mm = *reinterpret_cast<const uchar2*>(mb + ridx[r]);
      m0[r] = mm.x; m1[r] = mm.y;
    }
  }

  // ---- main accumulation: each E float2 read feeds 4 u-rows (halved LDS bytes/FLOP) ----
  // acc = sum_h v_h / (E_h*D_h + 1), 4 h at a time with ONE rcp:
  //   sum v_i/t_i = ((v0 t1 + v1 t0) t2 t3 + (v2 t3 + v3 t2) t0 t1) / (t0 t1 t2 t3)
  float acc[4][2] = {{0.f,0.f},{0.f,0.f},{0.f,0.f},{0.f,0.f}};

  auto quad = [](const float4& vv, float ea, float eb, float ec, float ed,
                 const float4& d, float& a) {
    float t0 = fmaf(ea, d.x, 1.0f);
    float t1 = fmaf(eb, d.y, 1.0f);
    float t2 = fmaf(ec, d.z, 1.0f);
    float t3 = fmaf(ed, d.w, 1.0f);
    float t01 = t0 * t1;
    float t23 = t2 * t3;
    float n01 = fmaf(vv.x, t1, vv.y * t0);
    float n23 = fmaf(vv.z, t3, vv.w * t2);
    float den = t01 * t23;
    float num = fmaf(n01, t23, n23 * t01);
    a = fmaf(num, __builtin_amdgcn_rcpf(den), a);
  };

  #pragma unroll 4
  for (int h4 = 0; h4 < H_ / 4; ++h4) {
    const int hh = h4 * 4;
    const float2 e0 = *reinterpret_cast<const float2*>(&E[hh + 0][s0]);
    const float2 e1 = *reinterpret_cast<const float2*>(&E[hh + 1][s0]);
    const float2 e2 = *reinterpret_cast<const float2*>(&E[hh + 2][s0]);
    const float2 e3 = *reinterpret_cast<const float2*>(&E[hh + 3][s0]);
    const float4 d0 = *reinterpret_cast<const float4*>(&decs[rg][0][hh]);  // LDS broadcast
    const float4 d1 = *reinterpret_cast<const float4*>(&decs[rg][1][hh]);  // LDS broadcast
    const float4 d2 = *reinterpret_cast<const float4*>(&decs[rg][2][hh]);  // LDS broadcast
    const float4 d3 = *reinterpret_cast<const float4*>(&decs[rg][3][hh]);  // LDS broadcast
    const float4 vv = *reinterpret_cast<const float4*>(vt + hh);           // uniform -> scalar load
    quad(vv, e0.x, e1.x, e2.x, e3.x, d0, acc[0][0]);
    quad(vv, e0.y, e1.y, e2.y, e3.y, d0, acc[0][1]);
    quad(vv, e0.x, e1.x, e2.x, e3.x, d1, acc[1][0]);
    quad(vv, e0.y, e1.y, e2.y, e3.y, d1, acc[1][1]);
    quad(vv, e0.x, e1.x, e2.x, e3.x, d2, acc[2][0]);
    quad(vv, e0.y, e1.y, e2.y, e3.y, d2, acc[2][1]);
    quad(vv, e0.x, e1.x, e2.x, e3.x, d3, acc[3][0]);
    quad(vv, e0.y, e1.y, e2.y, e3.y, d3, acc[3][1]);
  }

  // ---- mask + cross-wave-pair softmax + store ----
  const float negs = -103.6163291847321f * 10.0f;   // log(1e-45) * EXPLORATION_C
  const float vs10 = vsum_s * 10.0f;
  float p[4][2];
  #pragma unroll
  for (int r = 0; r < 4; ++r) {
    float sA = m0[r] ? fmaf(-20.0f, acc[r][0], vs10) : negs;
    float sB = m1[r] ? fmaf(-20.0f, acc[r][1], vs10) : negs;
    p[r][0] = sA; p[r][1] = sB;
    float mx = fmaxf(sA, sB);
    #pragma unroll
    for (int off = 32; off > 0; off >>= 1) mx = fmaxf(mx, __shfl_xor(mx, off, 64));
    if (lane == 0) redmax[rg][r][sh] = mx;
  }
  __syncthreads();
  #pragma unroll
  for (int r = 0; r < 4; ++r) {
    const float gmx = fmaxf(redmax[rg][r][0], redmax[rg][r][1]);
    float pa = __expf(p[r][0] - gmx);
    float pb = __expf(p[r][1] - gmx);
    p[r][0] = pa; p[r][1] = pb;
    float sm = pa + pb;
    #pragma unroll
    for (int off = 32; off > 0; off >>= 1) sm += __shfl_xor(sm, off, 64);
    if (lane == 0) redsum[rg][r][sh] = sm;
  }
  __syncthreads();
  #pragma unroll
  for (int r = 0; r < 4; ++r) {
    if (uval[r]) {
      const float inv = __builtin_amdgcn_rcpf(redsum[rg][r][0] + redsum[rg][r][1]);
      float2 o; o.x = p[r][0] * inv; o.y = p[r][1] * inv;
      *reinterpret_cast<float2*>(out + ridx[r]) = o;
    }
  }
}

extern "C" void kernel_launch(void* const* d_in, const int* in_sizes, int n_in,
                              void* d_out, int out_size, void* d_ws, size_t ws_size,
                              hipStream_t stream) {
  const float* user   = (const float*)d_in[0];
  const float* server = (const float*)d_in[1];
  const int*   masks  = (const int*)d_in[2];
  const float* Wu = (const float*)d_in[3];
  const float* bu = (const float*)d_in[4];
  const float* Ws = (const float*)d_in[5];
  const float* bs = (const float*)d_in[6];
  const float* W1 = (const float*)d_in[7];
  const float* W2 = (const float*)d_in[8];
  const float* vt = (const float*)d_in[9];
  float* out = (float*)d_out;
  (void)in_sizes; (void)n_in; (void)out_size; (void)d_ws; (void)ws_size;

  attn_kernel<<<dim3(B_ * ((U_ + UTILE - 1) / UTILE)), dim3(TPB), 0, stream>>>(
      user, server, masks, Wu, bu, Ws, bs, W1, W2, vt, out);
}